// Round 22
// baseline (95.878 us; speedup 1.0000x reference)
//
#include <hip/hip_runtime.h>
#include <hip/hip_fp16.h>
#include <math.h>

#define B_ 2
#define N_ 4096
#define DIM_ 256
#define HEADS_ 4
#define DH_ 64
#define KNN_ 32
#define INNER_ 256       // HEADS*DH
#define QKVW_ 768        // 3*INNER
#define HB_ 256          // histogram bins
#define CAND_ 512        // boundary-bin candidate cap
#define M_ 8192          // B_*N_

typedef _Float16 f16x8 __attribute__((ext_vector_type(8)));
typedef _Float16 f16x4 __attribute__((ext_vector_type(4)));
typedef _Float16 f16x2 __attribute__((ext_vector_type(2)));
typedef float    f32x4 __attribute__((ext_vector_type(4)));

#if defined(__has_builtin)
#if __has_builtin(__builtin_amdgcn_fdot2)
#define HAVE_FDOT2 1
#endif
#endif

static __device__ __forceinline__ float fdot2f(f16x2 a, f16x2 b, float c) {
#ifdef HAVE_FDOT2
    return __builtin_amdgcn_fdot2(a, b, c, false);
#else
    return (float)a[0]*(float)b[0] + (float)a[1]*(float)b[1] + c;
#endif
}

static __device__ __forceinline__ unsigned long long ullmin2(unsigned long long a, unsigned long long b) {
    return a < b ? a : b;
}

// sin/cos of (2*pi*rev) via HW trans ops; rev >= 0.
static __device__ __forceinline__ void sincos_rev(float rev, float* s, float* c) {
    const float fr = rev - floorf(rev);      // v_fract
    float ss, cc;
    asm("v_sin_f32 %0, %1" : "=v"(ss) : "v"(fr));
    asm("v_cos_f32 %0, %1" : "=v"(cc) : "v"(fr));
    *s = ss; *c = cc;
}

// ---------------- prep: wconv x2 + coors SoA + feats f32->f16, one kernel ----------------
__global__ __launch_bounds__(256) void prep_kernel(const float* __restrict__ w_qkv,
                                                   const float* __restrict__ w_out,
                                                   const float* __restrict__ coors,
                                                   const float* __restrict__ feats,
                                                   _Float16* __restrict__ wqkvT,
                                                   _Float16* __restrict__ woutT,
                                                   float* __restrict__ xs,
                                                   float* __restrict__ ys,
                                                   float* __restrict__ zs,
                                                   _Float16* __restrict__ feats_h) {
    __shared__ float tl[32][33];
    const int blk = blockIdx.x;
    const int tx = threadIdx.x & 31, ty = threadIdx.x >> 5;
    if (blk < 256) {
        const float* in; _Float16* out; int Nn, n0, k0;
        if (blk < 192) { in = w_qkv; out = wqkvT; Nn = QKVW_; n0 = (blk % 24) * 32; k0 = (blk / 24) * 32; }
        else { const int b2 = blk - 192; in = w_out; out = woutT; Nn = DIM_; n0 = (b2 % 8) * 32; k0 = (b2 / 8) * 32; }
        #pragma unroll
        for (int r = 0; r < 4; ++r)
            tl[ty + r*8][tx] = in[(size_t)(k0 + ty + r*8) * Nn + n0 + tx];
        __syncthreads();
        #pragma unroll
        for (int r = 0; r < 4; ++r)
            out[(size_t)(n0 + ty + r*8) * 256 + k0 + tx] = (_Float16)(tl[tx][ty + r*8] * 64.0f);
    } else if (blk < 288) {
        const int p = (blk - 256) * 256 + threadIdx.x;   // 8192 points
        const float x = coors[p*3+0], y = coors[p*3+1], z = coors[p*3+2];
        xs[p] = x; ys[p] = y; zs[p] = z;
    } else {
        const size_t base = ((size_t)(blk - 288) * 256 + threadIdx.x) * 8;
        const float4 a0 = *(const float4*)(feats + base);
        const float4 a1 = *(const float4*)(feats + base + 4);
        f16x8 h;
        h[0] = (_Float16)a0.x; h[1] = (_Float16)a0.y;
        h[2] = (_Float16)a0.z; h[3] = (_Float16)a0.w;
        h[4] = (_Float16)a1.x; h[5] = (_Float16)a1.y;
        h[6] = (_Float16)a1.z; h[7] = (_Float16)a1.w;
        *(f16x8*)(feats_h + base) = h;
    }
}

// ---------------- MFMA GEMM, BK=64 (4 k-iterations, half the barriers) ----------------
// OUT_MODE: 0 = f32 linear (+bias), 2 = qkv-split (q_buf x0.125 + k4||v4).
// TN = tile width (128 or 64). Wave grid 2x2; wave covers 64 rows x TN/2 cols.
template <int OUT_MODE, int TN>
__global__ __launch_bounds__(256) void mfma_gemm_kernel(const _Float16* __restrict__ A,
                                                        const _Float16* __restrict__ Bt,
                                                        const float* __restrict__ bias,
                                                        void* __restrict__ Cp,
                                                        int Nn) {
    constexpr int NI = TN / 32;     // N-frags per wave
    __shared__ _Float16 As[8192];   // [kgrp 0..7][row 0..127][8]  (16 KB)
    __shared__ _Float16 Bs[TN*64];  // [kq 0..7][col 0..TN-1][8]
    const int t = threadIdx.x;
    const int w = t >> 6, l = t & 63;
    const int wr = w >> 1, wc = w & 1;
    const int lr = l & 15, kg = l >> 4;
    const int row0 = blockIdx.y * 128, col0 = blockIdx.x * TN;

    f32x4 acc[4][NI];
    #pragma unroll
    for (int mi = 0; mi < 4; ++mi)
        #pragma unroll
        for (int ni = 0; ni < NI; ++ni)
            acc[mi][ni] = (f32x4){0.0f, 0.0f, 0.0f, 0.0f};

    for (int k0 = 0; k0 < 256; k0 += 64) {
        __syncthreads();
        // stage A: 128 rows x 64 k = 1024 slots of f16x8
        #pragma unroll
        for (int r = 0; r < 4; ++r) {
            const int u = r*256 + t;
            const int row = u >> 3, kgrp = u & 7;
            *(f16x8*)&As[((kgrp<<7) + row)*8] =
                *(const f16x8*)(A + (size_t)(row0 + row)*256 + k0 + kgrp*8);
        }
        // stage B: TN cols x 64 k = TN*8 slots of f16x8
        #pragma unroll
        for (int r = 0; r < TN/32; ++r) {
            const int u = r*256 + t;
            const int col = u >> 3, kq = u & 7;
            *(f16x8*)&Bs[((kq*TN) + col)*8] =
                *(const f16x8*)(Bt + (size_t)(col0 + col)*256 + k0 + kq*8);
        }
        __syncthreads();
        #pragma unroll
        for (int kk = 0; kk < 2; ++kk) {        // two 32-k MFMA steps per stage
            f16x8 af[4], bf[NI];
            #pragma unroll
            for (int mi = 0; mi < 4; ++mi)
                af[mi] = *(const f16x8*)&As[(((kk*4 + kg)<<7) + wr*64 + mi*16 + lr)*8];
            #pragma unroll
            for (int ni = 0; ni < NI; ++ni)
                bf[ni] = *(const f16x8*)&Bs[(((kk*4 + kg)*TN) + wc*(TN/2) + ni*16 + lr)*8];
            #pragma unroll
            for (int mi = 0; mi < 4; ++mi)
                #pragma unroll
                for (int ni = 0; ni < NI; ++ni)
                    acc[mi][ni] = __builtin_amdgcn_mfma_f32_16x16x32_f16(af[mi], bf[ni], acc[mi][ni], 0, 0, 0);
        }
    }

    #pragma unroll
    for (int mi = 0; mi < 4; ++mi)
        #pragma unroll
        for (int ni = 0; ni < NI; ++ni) {
            const int col = col0 + wc*(TN/2) + ni*16 + lr;
            const float bv = (OUT_MODE == 0 && bias) ? bias[col] : 0.0f;
            #pragma unroll
            for (int r = 0; r < 4; ++r) {
                const int row = row0 + wr*64 + mi*16 + kg*4 + r;
                const float v = acc[mi][ni][r] * 0.015625f + bv;
                if constexpr (OUT_MODE == 0) {
                    ((float*)Cp)[(size_t)row * Nn + col] = v;
                } else {
                    _Float16* qb = (_Float16*)Cp;
                    _Float16* kvb = qb + (size_t)M_ * 256;
                    if (col < 256) {
                        qb[(size_t)row * 256 + col] = (_Float16)(v * 0.125f);  // fold dh^-0.5
                    } else {
                        const int d = col & 255;
                        const int isv = (col >> 9) & 1;
                        kvb[(size_t)row * 512 + ((d >> 2) << 3) + (isv << 2) + (d & 3)] = (_Float16)v;
                    }
                }
            }
        }
}

// ---------------- fused KNN + attention, one block per query ----------------
struct KnnSmem {
    int hist[HB_];                   // 1 KB
    unsigned long long cand[CAND_];  // 4 KB
    float tminf[256];                // 1 KB
};
union FusedSmem {
    KnnSmem k;
    float po[HEADS_ * INNER_];       // 4 KB PV partials
};

__global__ __launch_bounds__(256, 8) void knn_attn_kernel(
        const float* __restrict__ xs, const float* __restrict__ ys,
        const float* __restrict__ zs,
        const _Float16* __restrict__ q_buf, const _Float16* __restrict__ kv_buf,
        const float* __restrict__ w_c1, const float* __restrict__ b_c1,
        const float* __restrict__ w_c2, const float* __restrict__ b_c2,
        const float* __restrict__ ln_b,
        _Float16* __restrict__ out_pre, float* __restrict__ coors_out) {
    __shared__ FusedSmem u;                 // 6 KB
    __shared__ float qkl[KNN_][HEADS_];
    __shared__ float attnl[KNN_][HEADS_];
    __shared__ float coorw[KNN_];
    __shared__ float distl[KNN_];           // raw dist (phase A prologue)
    __shared__ float ul[KNN_][3];
    __shared__ int   njl[KNN_];
    __shared__ float Msh;
    __shared__ int   bsh, clsh, candcnt, outcnt;

    const int bi = blockIdx.x;
    const int b = bi >> 12;            // N_ = 4096
    const int t = threadIdx.x;
    const float* xb = xs + (size_t)b * N_;
    const float* yb = ys + (size_t)b * N_;
    const float* zb = zs + (size_t)b * N_;
    const float xi = xs[bi], yi = ys[bi], zi = zs[bi];

    // hoisted q load (latency hides under phase K)
    const f16x4 qh = *(const f16x4*)(q_buf + (size_t)bi * 256 + 4*(t & 63));
    const f16x2 q01 = {qh[0], qh[1]}, q23 = {qh[2], qh[3]};

    // ---------- phase K: exact KNN on squared distances ----------
    float dreg[16];                    // 16 squared distances, static-indexed
    float mymin = INFINITY;
    #pragma unroll
    for (int r = 0; r < N_/(256*4); ++r) {
        const int p = t + r*256;
        const float4 xv = *(const float4*)(xb + 4*p);
        const float4 yv = *(const float4*)(yb + 4*p);
        const float4 zv = *(const float4*)(zb + 4*p);
        float4 dv;
        {   float dx = xi - xv.x, dy = yi - yv.x, dz = zi - zv.x;
            dv.x = dx*dx + dy*dy + dz*dz; }
        {   float dx = xi - xv.y, dy = yi - yv.y, dz = zi - zv.y;
            dv.y = dx*dx + dy*dy + dz*dz; }
        {   float dx = xi - xv.z, dy = yi - yv.z, dz = zi - zv.z;
            dv.z = dx*dx + dy*dy + dz*dz; }
        {   float dx = xi - xv.w, dy = yi - yv.w, dz = zi - zv.w;
            dv.w = dx*dx + dy*dy + dz*dz; }
        dreg[r*4+0] = dv.x; dreg[r*4+1] = dv.y;
        dreg[r*4+2] = dv.z; dreg[r*4+3] = dv.w;
        mymin = fminf(mymin, fminf(fminf(dv.x, dv.y), fminf(dv.z, dv.w)));
    }
    u.k.tminf[t] = mymin;
    u.k.hist[t] = 0;
    if (t == 0) { candcnt = 0; outcnt = 0; }
    __syncthreads();

    if (t < 64) {
        float m4 = fmaxf(fmaxf(u.k.tminf[t], u.k.tminf[t+64]),
                         fmaxf(u.k.tminf[t+128], u.k.tminf[t+192]));
        #pragma unroll
        for (int off = 32; off; off >>= 1) m4 = fmaxf(m4, __shfl_xor(m4, off));
        if (t == 0) Msh = fmaxf(m4, 1e-30f);
    }
    __syncthreads();

    const float Mv = Msh;                       // upper bound on d32^2
    const float scale = (float)(HB_ - 1) / Mv;

    #pragma unroll
    for (int r = 0; r < 16; ++r) {
        const float d = dreg[r];
        if (d <= Mv) {
            const int bin = (int)fminf(d * scale, (float)(HB_ - 1));
            atomicAdd(&u.k.hist[bin], 1);
        }
    }
    __syncthreads();

    if (t < 64) {
        int s = 0;
        #pragma unroll
        for (int k = 0; k < HB_/64; ++k) s += u.k.hist[t*(HB_/64) + k];
        int inc = s;
        #pragma unroll
        for (int off = 1; off < 64; off <<= 1) {
            const int v = __shfl_up(inc, off);
            if (t >= off) inc += v;
        }
        const int excl = inc - s;
        if (excl < KNN_ && inc >= KNN_) {
            int cum = excl;
            #pragma unroll
            for (int k = 0; k < HB_/64; ++k) {
                const int c = u.k.hist[t*(HB_/64) + k];
                if (cum + c >= KNN_) { bsh = t*(HB_/64) + k; clsh = cum; break; }
                cum += c;
            }
        }
    }
    __syncthreads();

    const int bbin = bsh, c_less = clsh;

    #pragma unroll
    for (int r = 0; r < N_/(256*4); ++r) {
        #pragma unroll
        for (int e = 0; e < 4; ++e) {
            const float d = dreg[r*4+e];
            if (d <= Mv) {
                const int j = 4*(t + r*256) + e;
                const int bin = (int)fminf(d * scale, (float)(HB_ - 1));
                if (bin < bbin) {
                    const int slot = atomicAdd(&outcnt, 1);
                    njl[slot] = j;
                } else if (bin == bbin) {
                    const int c = atomicAdd(&candcnt, 1);
                    if (c < CAND_) {
                        // exact reference key for tie-break: bits of sqrt(d2)
                        u.k.cand[c] = ((unsigned long long)__float_as_uint(sqrtf(d)) << 32) | (unsigned)j;
                    }
                }
            }
        }
    }
    __syncthreads();

    const int m = KNN_ - c_less;
    const int e = candcnt;
    if (e <= CAND_) {
        if (t < 64) {
            for (int r = 0; r < m; ++r) {
                unsigned long long v = ~0ULL;
                for (int idx = t; idx < e; idx += 64) v = ullmin2(v, u.k.cand[idx]);
                #pragma unroll
                for (int off = 32; off; off >>= 1) v = ullmin2(v, __shfl_xor(v, off));
                if (t == 0) njl[c_less + r] = (int)(v & 0xffffffffu);
                for (int idx = t; idx < e; idx += 64)
                    if (u.k.cand[idx] == v) u.k.cand[idx] = ~0ULL;
            }
        }
    } else if (t == 0) {
        // degenerate fallback (massively tied distances) — recompute, unused
        for (int r = 0; r < m; ++r) {
            unsigned long long best = ~0ULL;
            for (int jj = 0; jj < N_; ++jj) {
                const float dx = xi - xb[jj], dy = yi - yb[jj], dz = zi - zb[jj];
                const float d2 = dx*dx + dy*dy + dz*dz;
                if (d2 <= Mv) {
                    const int bin = (int)fminf(d2 * scale, (float)(HB_ - 1));
                    if (bin == bbin) {
                        bool skip = false;
                        for (int q = 0; q < r; ++q) if (njl[c_less + q] == jj) skip = true;
                        if (!skip) {
                            const unsigned long long key =
                                ((unsigned long long)__float_as_uint(sqrtf(d2)) << 32) | (unsigned)jj;
                            best = ullmin2(best, key);
                        }
                    }
                }
            }
            njl[c_less + r] = (int)(best & 0xffffffffu);
        }
    }
    __syncthreads();   // knn scratch dead; po (aliased) live from here

    // ---------- phase A: attention ----------
    const int w = t >> 6;                   // wave id
    const int l = t & 63;                   // lane
    const int h = l >> 4;                   // head for this lane's dims

    if (t < KNN_) {
        const int nj = njl[t];
        const float dx = xi - xb[nj];
        const float dy = yi - yb[nj];
        const float dz = zi - zb[nj];
        const float dist = sqrtf(dx*dx + dy*dy + dz*dz);   // identical expr -> identical bits
        distl[t] = dist;
        const float den = fmaxf(dist, 1e-8f);
        ul[t][0] = dx / den; ul[t][1] = dy / den; ul[t][2] = dz / den;
    }

    const int li = l & 15;
    const bool rot = li < 8;
    const float invf0r = exp2f(-(float)(2*li    ) * 0.8304820237218407f) * 0.15915494309189535f;
    const float invf1r = exp2f(-(float)(2*li + 1) * 0.8304820237218407f) * 0.15915494309189535f;
    const _Float16* kvb = kv_buf + (size_t)b * N_ * 512;
    __syncthreads();

    // issue ALL 8 gathers upfront (8 dwordx4 in flight; latency amortized)
    f16x8 kvr[8];
    #pragma unroll
    for (int jj = 0; jj < 8; ++jj)
        kvr[jj] = *(const f16x8*)(kvb + (size_t)njl[w*8 + jj] * 512 + l*8);

    f16x2 vf01[8], vf23[8];                 // rotated V in registers
    #pragma unroll
    for (int jj = 0; jj < 8; ++jj) {
        const int j = w*8 + jj;
        const f16x8 kv = kvr[jj];
        f16x2 k01 = {kv[0], kv[1]}, k23 = {kv[2], kv[3]};
        f16x2 v01 = {kv[4], kv[5]}, v23 = {kv[6], kv[7]};
        if (rot) {
            const float d100 = distl[j] * 100.0f;
            float s0, c0, s1, c1;
            sincos_rev(d100 * invf0r, &s0, &c0);
            sincos_rev(d100 * invf1r, &s1, &c1);
            const f16x2 cc0 = {(_Float16)c0, (_Float16)c0};
            const f16x2 sn0 = {(_Float16)(-s0), (_Float16)s0};
            const f16x2 cc1 = {(_Float16)c1, (_Float16)c1};
            const f16x2 sn1 = {(_Float16)(-s1), (_Float16)s1};
            const f16x2 k10 = {k01[1], k01[0]};
            const f16x2 k32 = {k23[1], k23[0]};
            const f16x2 v10 = {v01[1], v01[0]};
            const f16x2 v32 = {v23[1], v23[0]};
            k01 = k01*cc0 + k10*sn0;
            k23 = k23*cc1 + k32*sn1;
            v01 = v01*cc0 + v10*sn0;
            v23 = v23*cc1 + v32*sn1;
        }
        vf01[jj] = v01; vf23[jj] = v23;
        float p = fdot2f(k01, q01, fdot2f(k23, q23, 0.0f));
        p += __shfl_xor(p, 1);
        p += __shfl_xor(p, 2);
        p += __shfl_xor(p, 4);
        p += __shfl_xor(p, 8);
        if (li == 0) qkl[j][h] = p;            // dh^-0.5 folded into q
    }
    __syncthreads();

    {   // softmax over j for head w (lanes 0..31 of wave w)
        const int d = l;
        const float x = (d < KNN_) ? qkl[d][w] : -INFINITY;
        float mx = x;
        #pragma unroll
        for (int off = 32; off; off >>= 1) mx = fmaxf(mx, __shfl_xor(mx, off));
        const float ev = __expf(x - mx);
        float s = ev;
        #pragma unroll
        for (int off = 32; off; off >>= 1) s += __shfl_xor(s, off);
        if (d < KNN_) attnl[d][w] = ev / s;
    }

    {   // coord-MLP distributed: thread t -> j = t>>3, cells mh0, mh0+1
        const int j = t >> 3;
        const int mh0 = (t & 7) * 2;
        const float a0 = qkl[j][0], a1 = qkl[j][1], a2 = qkl[j][2], a3 = qkl[j][3];
        float cw = 0.0f;
        #pragma unroll
        for (int ee = 0; ee < 2; ++ee) {
            const int mh = mh0 + ee;
            const float hv = a0*w_c1[0*16+mh] + a1*w_c1[1*16+mh]
                           + a2*w_c1[2*16+mh] + a3*w_c1[3*16+mh] + b_c1[mh];
            const float g = 0.5f * hv * (1.0f + erff(hv * 0.70710678118654752440f));
            cw += g * w_c2[mh];
        }
        cw += __shfl_xor(cw, 1);
        cw += __shfl_xor(cw, 2);
        cw += __shfl_xor(cw, 4);
        if ((t & 7) == 0) coorw[j] = cw + b_c2[0];
    }
    __syncthreads();   // REQUIRED: PV reads attnl columns written by OTHER waves

    {   // PV per-wave partial over this wave's 8 neighbors (V in regs)
        float o0 = 0.0f, o1 = 0.0f, o2 = 0.0f, o3 = 0.0f;
        #pragma unroll
        for (int jj = 0; jj < 8; ++jj) {
            const float a = attnl[w*8 + jj][h];
            o0 += a * (float)vf01[jj][0];
            o1 += a * (float)vf01[jj][1];
            o2 += a * (float)vf23[jj][0];
            o3 += a * (float)vf23[jj][1];
        }
        *(float4*)&u.po[w * INNER_ + 4*l] = make_float4(o0, o1, o2, o3);
    }
    __syncthreads();

    {   // combine 4 wave-partials for dim t
        const float o = u.po[t] + u.po[INNER_ + t] + u.po[2*INNER_ + t] + u.po[3*INNER_ + t];
        out_pre[(size_t)bi * INNER_ + t] = (_Float16)o;
    }

    if (t < 3) {
        float acc = 0.0f;
        #pragma unroll
        for (int j = 0; j < KNN_; ++j) acc += coorw[j] * ul[j][t];
        coors_out[(size_t)bi * 3 + t] = acc * ln_b[0];
    }
}

extern "C" void kernel_launch(void* const* d_in, const int* in_sizes, int n_in,
                              void* d_out, int out_size, void* d_ws, size_t ws_size,
                              hipStream_t stream) {
    (void)in_sizes; (void)n_in; (void)out_size; (void)ws_size;
    const float* feats = (const float*)d_in[0];
    const float* coors = (const float*)d_in[1];
    const float* w_qkv = (const float*)d_in[2];
    const float* w_out = (const float*)d_in[3];
    const float* b_out = (const float*)d_in[4];
    const float* w_c1  = (const float*)d_in[5];
    const float* b_c1  = (const float*)d_in[6];
    const float* w_c2  = (const float*)d_in[7];
    const float* b_c2  = (const float*)d_in[8];
    const float* ln_b  = (const float*)d_in[10];   // ln_g (d_in[9]) is dead

    const int M = M_;                               // 8192
    _Float16* q_buf    = (_Float16*)d_ws;                         // M*256 f16 (x dh^-0.5)
    _Float16* kv_buf   = q_buf + (size_t)M * 256;                 // M*512 f16 (k4||v4)
    _Float16* out_pre  = kv_buf + (size_t)M * 512;                // M*256 f16
    _Float16* wqkvT    = out_pre + (size_t)M * INNER_;            // 768*256 f16
    _Float16* woutT    = wqkvT + (size_t)QKVW_ * DIM_;            // 256*256 f16
    _Float16* feats_h  = woutT + (size_t)DIM_ * DIM_;             // M*256 f16
    float*    xs       = (float*)(feats_h + (size_t)M * DIM_);    // M
    float*    ys       = xs + M;
    float*    zs       = ys + M;

    float* out_main  = (float*)d_out;               // 8192*256
    float* out_coors = out_main + (size_t)M * DIM_; // 8192*3

    // prep: weight transposes + coords SoA + feats f32->f16
    prep_kernel<<<288 + (M*DIM_)/2048, 256, 0, stream>>>(
        w_qkv, w_out, coors, feats, wqkvT, woutT, xs, ys, zs, feats_h);

    // qkv = feats_h @ w_qkv  -> q_buf (x0.125) + kv-interleaved kv_buf
    mfma_gemm_kernel<2, 128><<<dim3(QKVW_/128, M/128), 256, 0, stream>>>(
        feats_h, wqkvT, nullptr, q_buf, QKVW_);

    // fused exact-KNN + attention
    knn_attn_kernel<<<M, 256, 0, stream>>>(xs, ys, zs, q_buf, kv_buf,
                                           w_c1, b_c1, w_c2, b_c2, ln_b,
                                           out_pre, out_coors);

    // out = out_pre @ w_out + b_out  (TN=64: 256 blocks = exactly 1 wave)
    mfma_gemm_kernel<0, 64><<<dim3(DIM_/64, M/128), 256, 0, stream>>>(
        out_pre, woutT, b_out, out_main, DIM_);
}

// Round 23
// 94.457 us; speedup vs baseline: 1.0150x; 1.0150x over previous
//
#include <hip/hip_runtime.h>
#include <hip/hip_fp16.h>
#include <math.h>

#define B_ 2
#define N_ 4096
#define DIM_ 256
#define HEADS_ 4
#define DH_ 64
#define KNN_ 32
#define INNER_ 256       // HEADS*DH
#define QKVW_ 768        // 3*INNER
#define HB_ 256          // histogram bins
#define CAND_ 512        // boundary-bin candidate cap
#define M_ 8192          // B_*N_

typedef _Float16 f16x8 __attribute__((ext_vector_type(8)));
typedef _Float16 f16x4 __attribute__((ext_vector_type(4)));
typedef _Float16 f16x2 __attribute__((ext_vector_type(2)));
typedef float    f32x4 __attribute__((ext_vector_type(4)));

#if defined(__has_builtin)
#if __has_builtin(__builtin_amdgcn_fdot2)
#define HAVE_FDOT2 1
#endif
#endif

static __device__ __forceinline__ float fdot2f(f16x2 a, f16x2 b, float c) {
#ifdef HAVE_FDOT2
    return __builtin_amdgcn_fdot2(a, b, c, false);
#else
    return (float)a[0]*(float)b[0] + (float)a[1]*(float)b[1] + c;
#endif
}

static __device__ __forceinline__ unsigned long long ullmin2(unsigned long long a, unsigned long long b) {
    return a < b ? a : b;
}

// sin/cos of (2*pi*rev) via HW trans ops; rev >= 0.
static __device__ __forceinline__ void sincos_rev(float rev, float* s, float* c) {
    const float fr = rev - floorf(rev);      // v_fract
    float ss, cc;
    asm("v_sin_f32 %0, %1" : "=v"(ss) : "v"(fr));
    asm("v_cos_f32 %0, %1" : "=v"(cc) : "v"(fr));
    *s = ss; *c = cc;
}

// ---------------- prep: wconv x2 + coors SoA + feats f32->f16, one kernel ----------------
__global__ __launch_bounds__(256) void prep_kernel(const float* __restrict__ w_qkv,
                                                   const float* __restrict__ w_out,
                                                   const float* __restrict__ coors,
                                                   const float* __restrict__ feats,
                                                   _Float16* __restrict__ wqkvT,
                                                   _Float16* __restrict__ woutT,
                                                   float* __restrict__ xs,
                                                   float* __restrict__ ys,
                                                   float* __restrict__ zs,
                                                   _Float16* __restrict__ feats_h) {
    __shared__ float tl[32][33];
    const int blk = blockIdx.x;
    const int tx = threadIdx.x & 31, ty = threadIdx.x >> 5;
    if (blk < 256) {
        const float* in; _Float16* out; int Nn, n0, k0;
        if (blk < 192) { in = w_qkv; out = wqkvT; Nn = QKVW_; n0 = (blk % 24) * 32; k0 = (blk / 24) * 32; }
        else { const int b2 = blk - 192; in = w_out; out = woutT; Nn = DIM_; n0 = (b2 % 8) * 32; k0 = (b2 / 8) * 32; }
        #pragma unroll
        for (int r = 0; r < 4; ++r)
            tl[ty + r*8][tx] = in[(size_t)(k0 + ty + r*8) * Nn + n0 + tx];
        __syncthreads();
        #pragma unroll
        for (int r = 0; r < 4; ++r)
            out[(size_t)(n0 + ty + r*8) * 256 + k0 + tx] = (_Float16)(tl[tx][ty + r*8] * 64.0f);
    } else if (blk < 288) {
        const int p = (blk - 256) * 256 + threadIdx.x;   // 8192 points
        const float x = coors[p*3+0], y = coors[p*3+1], z = coors[p*3+2];
        xs[p] = x; ys[p] = y; zs[p] = z;
    } else {
        const size_t base = ((size_t)(blk - 288) * 256 + threadIdx.x) * 8;
        const float4 a0 = *(const float4*)(feats + base);
        const float4 a1 = *(const float4*)(feats + base + 4);
        f16x8 h;
        h[0] = (_Float16)a0.x; h[1] = (_Float16)a0.y;
        h[2] = (_Float16)a0.z; h[3] = (_Float16)a0.w;
        h[4] = (_Float16)a1.x; h[5] = (_Float16)a1.y;
        h[6] = (_Float16)a1.z; h[7] = (_Float16)a1.w;
        *(f16x8*)(feats_h + base) = h;
    }
}

// ---------------- MFMA GEMM, BK=32 (proven best at these grid sizes) ----------------
// OUT_MODE: 0 = f32 linear (+bias), 2 = qkv-split (q_buf x0.125 + k4||v4).
// TN = tile width (128 or 64). Wave grid 2x2; wave covers 64 rows x TN/2 cols.
template <int OUT_MODE, int TN>
__global__ __launch_bounds__(256) void mfma_gemm_kernel(const _Float16* __restrict__ A,
                                                        const _Float16* __restrict__ Bt,
                                                        const float* __restrict__ bias,
                                                        void* __restrict__ Cp,
                                                        int Nn) {
    constexpr int NI = TN / 32;     // N-frags per wave
    __shared__ _Float16 As[4096];   // 128 rows x 32 k  (8 KB)
    __shared__ _Float16 Bs[TN*32];  // TN cols x 32 k
    const int t = threadIdx.x;
    const int w = t >> 6, l = t & 63;
    const int wr = w >> 1, wc = w & 1;
    const int lr = l & 15, kg = l >> 4;
    const int row0 = blockIdx.y * 128, col0 = blockIdx.x * TN;

    f32x4 acc[4][NI];
    #pragma unroll
    for (int mi = 0; mi < 4; ++mi)
        #pragma unroll
        for (int ni = 0; ni < NI; ++ni)
            acc[mi][ni] = (f32x4){0.0f, 0.0f, 0.0f, 0.0f};

    for (int k0 = 0; k0 < 256; k0 += 32) {
        __syncthreads();
        #pragma unroll
        for (int r = 0; r < 2; ++r) {
            const int u = r*256 + t;
            const int row = u >> 2, kgrp = u & 3;
            *(f16x8*)&As[((kgrp<<7) + row)*8] =
                *(const f16x8*)(A + (size_t)(row0 + row)*256 + k0 + kgrp*8);
        }
        #pragma unroll
        for (int r = 0; r < TN/64; ++r) {
            const int u = r*256 + t;
            const int col = u >> 2, kq = u & 3;
            *(f16x8*)&Bs[((kq*TN) + col)*8] =
                *(const f16x8*)(Bt + (size_t)(col0 + col)*256 + k0 + kq*8);
        }
        __syncthreads();
        f16x8 af[4], bf[NI];
        #pragma unroll
        for (int mi = 0; mi < 4; ++mi)
            af[mi] = *(const f16x8*)&As[((kg<<7) + wr*64 + mi*16 + lr)*8];
        #pragma unroll
        for (int ni = 0; ni < NI; ++ni)
            bf[ni] = *(const f16x8*)&Bs[((kg*TN) + wc*(TN/2) + ni*16 + lr)*8];
        #pragma unroll
        for (int mi = 0; mi < 4; ++mi)
            #pragma unroll
            for (int ni = 0; ni < NI; ++ni)
                acc[mi][ni] = __builtin_amdgcn_mfma_f32_16x16x32_f16(af[mi], bf[ni], acc[mi][ni], 0, 0, 0);
    }

    #pragma unroll
    for (int mi = 0; mi < 4; ++mi)
        #pragma unroll
        for (int ni = 0; ni < NI; ++ni) {
            const int col = col0 + wc*(TN/2) + ni*16 + lr;
            const float bv = (OUT_MODE == 0 && bias) ? bias[col] : 0.0f;
            #pragma unroll
            for (int r = 0; r < 4; ++r) {
                const int row = row0 + wr*64 + mi*16 + kg*4 + r;
                const float v = acc[mi][ni][r] * 0.015625f + bv;
                if constexpr (OUT_MODE == 0) {
                    ((float*)Cp)[(size_t)row * Nn + col] = v;
                } else {
                    _Float16* qb = (_Float16*)Cp;
                    _Float16* kvb = qb + (size_t)M_ * 256;
                    if (col < 256) {
                        qb[(size_t)row * 256 + col] = (_Float16)(v * 0.125f);  // fold dh^-0.5
                    } else {
                        const int d = col & 255;
                        const int isv = (col >> 9) & 1;
                        kvb[(size_t)row * 512 + ((d >> 2) << 3) + (isv << 2) + (d & 3)] = (_Float16)v;
                    }
                }
            }
        }
}

// ---------------- fused KNN + attention, one block per query ----------------
struct KnnSmem {
    int hist[HB_];                   // 1 KB
    unsigned long long cand[CAND_];  // 4 KB
    float tminf[256];                // 1 KB
};
union FusedSmem {
    KnnSmem k;
    float po[HEADS_ * INNER_];       // 4 KB PV partials
};

__global__ __launch_bounds__(256, 8) void knn_attn_kernel(
        const float* __restrict__ xs, const float* __restrict__ ys,
        const float* __restrict__ zs,
        const _Float16* __restrict__ q_buf, const _Float16* __restrict__ kv_buf,
        const float* __restrict__ w_c1, const float* __restrict__ b_c1,
        const float* __restrict__ w_c2, const float* __restrict__ b_c2,
        const float* __restrict__ ln_b,
        _Float16* __restrict__ out_pre, float* __restrict__ coors_out) {
    __shared__ FusedSmem u;                 // 6 KB
    __shared__ float qkl[KNN_][HEADS_];
    __shared__ float attnl[KNN_][HEADS_];
    __shared__ float coorw[KNN_];
    __shared__ float distl[KNN_];           // raw dist (phase A prologue)
    __shared__ float ul[KNN_][3];
    __shared__ int   njl[KNN_];
    __shared__ float Msh;
    __shared__ int   bsh, clsh, candcnt, outcnt;

    const int bi = blockIdx.x;
    const int b = bi >> 12;            // N_ = 4096
    const int t = threadIdx.x;
    const float* xb = xs + (size_t)b * N_;
    const float* yb = ys + (size_t)b * N_;
    const float* zb = zs + (size_t)b * N_;
    const float xi = xs[bi], yi = ys[bi], zi = zs[bi];

    // hoisted q load (latency hides under phase K)
    const f16x4 qh = *(const f16x4*)(q_buf + (size_t)bi * 256 + 4*(t & 63));
    const f16x2 q01 = {qh[0], qh[1]}, q23 = {qh[2], qh[3]};

    // ---------- phase K: exact KNN on squared distances ----------
    float dreg[16];                    // 16 squared distances, static-indexed
    float mymin = INFINITY;
    #pragma unroll
    for (int r = 0; r < N_/(256*4); ++r) {
        const int p = t + r*256;
        const float4 xv = *(const float4*)(xb + 4*p);
        const float4 yv = *(const float4*)(yb + 4*p);
        const float4 zv = *(const float4*)(zb + 4*p);
        float4 dv;
        {   float dx = xi - xv.x, dy = yi - yv.x, dz = zi - zv.x;
            dv.x = dx*dx + dy*dy + dz*dz; }
        {   float dx = xi - xv.y, dy = yi - yv.y, dz = zi - zv.y;
            dv.y = dx*dx + dy*dy + dz*dz; }
        {   float dx = xi - xv.z, dy = yi - yv.z, dz = zi - zv.z;
            dv.z = dx*dx + dy*dy + dz*dz; }
        {   float dx = xi - xv.w, dy = yi - yv.w, dz = zi - zv.w;
            dv.w = dx*dx + dy*dy + dz*dz; }
        dreg[r*4+0] = dv.x; dreg[r*4+1] = dv.y;
        dreg[r*4+2] = dv.z; dreg[r*4+3] = dv.w;
        mymin = fminf(mymin, fminf(fminf(dv.x, dv.y), fminf(dv.z, dv.w)));
    }
    u.k.tminf[t] = mymin;
    u.k.hist[t] = 0;
    if (t == 0) { candcnt = 0; outcnt = 0; }
    __syncthreads();

    if (t < 64) {
        float m4 = fmaxf(fmaxf(u.k.tminf[t], u.k.tminf[t+64]),
                         fmaxf(u.k.tminf[t+128], u.k.tminf[t+192]));
        #pragma unroll
        for (int off = 32; off; off >>= 1) m4 = fmaxf(m4, __shfl_xor(m4, off));
        if (t == 0) Msh = fmaxf(m4, 1e-30f);
    }
    __syncthreads();

    const float Mv = Msh;                       // upper bound on d32^2
    const float scale = (float)(HB_ - 1) / Mv;

    #pragma unroll
    for (int r = 0; r < 16; ++r) {
        const float d = dreg[r];
        if (d <= Mv) {
            const int bin = (int)fminf(d * scale, (float)(HB_ - 1));
            atomicAdd(&u.k.hist[bin], 1);
        }
    }
    __syncthreads();

    if (t < 64) {
        int s = 0;
        #pragma unroll
        for (int k = 0; k < HB_/64; ++k) s += u.k.hist[t*(HB_/64) + k];
        int inc = s;
        #pragma unroll
        for (int off = 1; off < 64; off <<= 1) {
            const int v = __shfl_up(inc, off);
            if (t >= off) inc += v;
        }
        const int excl = inc - s;
        if (excl < KNN_ && inc >= KNN_) {
            int cum = excl;
            #pragma unroll
            for (int k = 0; k < HB_/64; ++k) {
                const int c = u.k.hist[t*(HB_/64) + k];
                if (cum + c >= KNN_) { bsh = t*(HB_/64) + k; clsh = cum; break; }
                cum += c;
            }
        }
    }
    __syncthreads();

    const int bbin = bsh, c_less = clsh;

    #pragma unroll
    for (int r = 0; r < N_/(256*4); ++r) {
        #pragma unroll
        for (int e = 0; e < 4; ++e) {
            const float d = dreg[r*4+e];
            if (d <= Mv) {
                const int j = 4*(t + r*256) + e;
                const int bin = (int)fminf(d * scale, (float)(HB_ - 1));
                if (bin < bbin) {
                    const int slot = atomicAdd(&outcnt, 1);
                    njl[slot] = j;
                } else if (bin == bbin) {
                    const int c = atomicAdd(&candcnt, 1);
                    if (c < CAND_) {
                        // exact reference key for tie-break: bits of sqrt(d2)
                        u.k.cand[c] = ((unsigned long long)__float_as_uint(sqrtf(d)) << 32) | (unsigned)j;
                    }
                }
            }
        }
    }
    __syncthreads();

    const int m = KNN_ - c_less;
    const int e = candcnt;
    if (e <= CAND_) {
        if (t < 64) {
            for (int r = 0; r < m; ++r) {
                unsigned long long v = ~0ULL;
                for (int idx = t; idx < e; idx += 64) v = ullmin2(v, u.k.cand[idx]);
                #pragma unroll
                for (int off = 32; off; off >>= 1) v = ullmin2(v, __shfl_xor(v, off));
                if (t == 0) njl[c_less + r] = (int)(v & 0xffffffffu);
                for (int idx = t; idx < e; idx += 64)
                    if (u.k.cand[idx] == v) u.k.cand[idx] = ~0ULL;
            }
        }
    } else if (t == 0) {
        // degenerate fallback (massively tied distances) — recompute, unused
        for (int r = 0; r < m; ++r) {
            unsigned long long best = ~0ULL;
            for (int jj = 0; jj < N_; ++jj) {
                const float dx = xi - xb[jj], dy = yi - yb[jj], dz = zi - zb[jj];
                const float d2 = dx*dx + dy*dy + dz*dz;
                if (d2 <= Mv) {
                    const int bin = (int)fminf(d2 * scale, (float)(HB_ - 1));
                    if (bin == bbin) {
                        bool skip = false;
                        for (int q = 0; q < r; ++q) if (njl[c_less + q] == jj) skip = true;
                        if (!skip) {
                            const unsigned long long key =
                                ((unsigned long long)__float_as_uint(sqrtf(d2)) << 32) | (unsigned)jj;
                            best = ullmin2(best, key);
                        }
                    }
                }
            }
            njl[c_less + r] = (int)(best & 0xffffffffu);
        }
    }
    __syncthreads();   // knn scratch dead; po (aliased) live from here

    // ---------- phase A: attention ----------
    const int w = t >> 6;                   // wave id
    const int l = t & 63;                   // lane
    const int h = l >> 4;                   // head for this lane's dims

    if (t < KNN_) {
        const int nj = njl[t];
        const float dx = xi - xb[nj];
        const float dy = yi - yb[nj];
        const float dz = zi - zb[nj];
        const float dist = sqrtf(dx*dx + dy*dy + dz*dz);   // identical expr -> identical bits
        distl[t] = dist;
        const float den = fmaxf(dist, 1e-8f);
        ul[t][0] = dx / den; ul[t][1] = dy / den; ul[t][2] = dz / den;
    }

    const int li = l & 15;
    const bool rot = li < 8;
    const float invf0r = exp2f(-(float)(2*li    ) * 0.8304820237218407f) * 0.15915494309189535f;
    const float invf1r = exp2f(-(float)(2*li + 1) * 0.8304820237218407f) * 0.15915494309189535f;
    const _Float16* kvb = kv_buf + (size_t)b * N_ * 512;
    __syncthreads();

    // issue ALL 8 gathers upfront (8 dwordx4 in flight; latency amortized)
    f16x8 kvr[8];
    #pragma unroll
    for (int jj = 0; jj < 8; ++jj)
        kvr[jj] = *(const f16x8*)(kvb + (size_t)njl[w*8 + jj] * 512 + l*8);

    f16x2 vf01[8], vf23[8];                 // rotated V in registers
    #pragma unroll
    for (int jj = 0; jj < 8; ++jj) {
        const int j = w*8 + jj;
        const f16x8 kv = kvr[jj];
        f16x2 k01 = {kv[0], kv[1]}, k23 = {kv[2], kv[3]};
        f16x2 v01 = {kv[4], kv[5]}, v23 = {kv[6], kv[7]};
        if (rot) {
            const float d100 = distl[j] * 100.0f;
            float s0, c0, s1, c1;
            sincos_rev(d100 * invf0r, &s0, &c0);
            sincos_rev(d100 * invf1r, &s1, &c1);
            const f16x2 cc0 = {(_Float16)c0, (_Float16)c0};
            const f16x2 sn0 = {(_Float16)(-s0), (_Float16)s0};
            const f16x2 cc1 = {(_Float16)c1, (_Float16)c1};
            const f16x2 sn1 = {(_Float16)(-s1), (_Float16)s1};
            const f16x2 k10 = {k01[1], k01[0]};
            const f16x2 k32 = {k23[1], k23[0]};
            const f16x2 v10 = {v01[1], v01[0]};
            const f16x2 v32 = {v23[1], v23[0]};
            k01 = k01*cc0 + k10*sn0;
            k23 = k23*cc1 + k32*sn1;
            v01 = v01*cc0 + v10*sn0;
            v23 = v23*cc1 + v32*sn1;
        }
        vf01[jj] = v01; vf23[jj] = v23;
        float p = fdot2f(k01, q01, fdot2f(k23, q23, 0.0f));
        p += __shfl_xor(p, 1);
        p += __shfl_xor(p, 2);
        p += __shfl_xor(p, 4);
        p += __shfl_xor(p, 8);
        if (li == 0) qkl[j][h] = p;            // dh^-0.5 folded into q
    }
    __syncthreads();

    {   // softmax over j for head w (lanes 0..31 of wave w)
        const int d = l;
        const float x = (d < KNN_) ? qkl[d][w] : -INFINITY;
        float mx = x;
        #pragma unroll
        for (int off = 32; off; off >>= 1) mx = fmaxf(mx, __shfl_xor(mx, off));
        const float ev = __expf(x - mx);
        float s = ev;
        #pragma unroll
        for (int off = 32; off; off >>= 1) s += __shfl_xor(s, off);
        if (d < KNN_) attnl[d][w] = ev / s;
    }

    {   // coord-MLP distributed: thread t -> j = t>>3, cells mh0, mh0+1
        const int j = t >> 3;
        const int mh0 = (t & 7) * 2;
        const float a0 = qkl[j][0], a1 = qkl[j][1], a2 = qkl[j][2], a3 = qkl[j][3];
        float cw = 0.0f;
        #pragma unroll
        for (int ee = 0; ee < 2; ++ee) {
            const int mh = mh0 + ee;
            const float hv = a0*w_c1[0*16+mh] + a1*w_c1[1*16+mh]
                           + a2*w_c1[2*16+mh] + a3*w_c1[3*16+mh] + b_c1[mh];
            const float g = 0.5f * hv * (1.0f + erff(hv * 0.70710678118654752440f));
            cw += g * w_c2[mh];
        }
        cw += __shfl_xor(cw, 1);
        cw += __shfl_xor(cw, 2);
        cw += __shfl_xor(cw, 4);
        if ((t & 7) == 0) coorw[j] = cw + b_c2[0];
    }
    __syncthreads();   // REQUIRED: PV reads attnl columns written by OTHER waves

    {   // PV per-wave partial over this wave's 8 neighbors (V in regs)
        float o0 = 0.0f, o1 = 0.0f, o2 = 0.0f, o3 = 0.0f;
        #pragma unroll
        for (int jj = 0; jj < 8; ++jj) {
            const float a = attnl[w*8 + jj][h];
            o0 += a * (float)vf01[jj][0];
            o1 += a * (float)vf01[jj][1];
            o2 += a * (float)vf23[jj][0];
            o3 += a * (float)vf23[jj][1];
        }
        *(float4*)&u.po[w * INNER_ + 4*l] = make_float4(o0, o1, o2, o3);
    }
    __syncthreads();

    {   // combine 4 wave-partials for dim t
        const float o = u.po[t] + u.po[INNER_ + t] + u.po[2*INNER_ + t] + u.po[3*INNER_ + t];
        out_pre[(size_t)bi * INNER_ + t] = (_Float16)o;
    }

    if (t < 3) {
        float acc = 0.0f;
        #pragma unroll
        for (int j = 0; j < KNN_; ++j) acc += coorw[j] * ul[j][t];
        coors_out[(size_t)bi * 3 + t] = acc * ln_b[0];
    }
}

extern "C" void kernel_launch(void* const* d_in, const int* in_sizes, int n_in,
                              void* d_out, int out_size, void* d_ws, size_t ws_size,
                              hipStream_t stream) {
    (void)in_sizes; (void)n_in; (void)out_size; (void)ws_size;
    const float* feats = (const float*)d_in[0];
    const float* coors = (const float*)d_in[1];
    const float* w_qkv = (const float*)d_in[2];
    const float* w_out = (const float*)d_in[3];
    const float* b_out = (const float*)d_in[4];
    const float* w_c1  = (const float*)d_in[5];
    const float* b_c1  = (const float*)d_in[6];
    const float* w_c2  = (const float*)d_in[7];
    const float* b_c2  = (const float*)d_in[8];
    const float* ln_b  = (const float*)d_in[10];   // ln_g (d_in[9]) is dead

    const int M = M_;                               // 8192
    _Float16* q_buf    = (_Float16*)d_ws;                         // M*256 f16 (x dh^-0.5)
    _Float16* kv_buf   = q_buf + (size_t)M * 256;                 // M*512 f16 (k4||v4)
    _Float16* out_pre  = kv_buf + (size_t)M * 512;                // M*256 f16
    _Float16* wqkvT    = out_pre + (size_t)M * INNER_;            // 768*256 f16
    _Float16* woutT    = wqkvT + (size_t)QKVW_ * DIM_;            // 256*256 f16
    _Float16* feats_h  = woutT + (size_t)DIM_ * DIM_;             // M*256 f16
    float*    xs       = (float*)(feats_h + (size_t)M * DIM_);    // M
    float*    ys       = xs + M;
    float*    zs       = ys + M;

    float* out_main  = (float*)d_out;               // 8192*256
    float* out_coors = out_main + (size_t)M * DIM_; // 8192*3

    // prep: weight transposes + coords SoA + feats f32->f16
    prep_kernel<<<288 + (M*DIM_)/2048, 256, 0, stream>>>(
        w_qkv, w_out, coors, feats, wqkvT, woutT, xs, ys, zs, feats_h);

    // qkv = feats_h @ w_qkv  -> q_buf (x0.125) + kv-interleaved kv_buf
    mfma_gemm_kernel<2, 128><<<dim3(QKVW_/128, M/128), 256, 0, stream>>>(
        feats_h, wqkvT, nullptr, q_buf, QKVW_);

    // fused exact-KNN + attention
    knn_attn_kernel<<<M, 256, 0, stream>>>(xs, ys, zs, q_buf, kv_buf,
                                           w_c1, b_c1, w_c2, b_c2, ln_b,
                                           out_pre, out_coors);

    // out = out_pre @ w_out + b_out  (TN=64: 256 blocks = exactly 1 wave)
    mfma_gemm_kernel<0, 64><<<dim3(DIM_/64, M/128), 256, 0, stream>>>(
        out_pre, woutT, b_out, out_main, DIM_);
}